// Round 3
// baseline (414.313 us; speedup 1.0000x reference)
//
#include <hip/hip_runtime.h>
#include <hip/hip_bf16.h>

#define NCH      256
#define NNB      262144
#define BN       64
#define NTILES   (NNB / BN)
#define NTHREADS 512
#define NENT     (NCH * 6)   // 1536... NOTE: 256*6 = 1536 entries per block

typedef __bf16        bf16x8 __attribute__((ext_vector_type(8)));
typedef float         f32x4  __attribute__((ext_vector_type(4)));
typedef unsigned int  u32x4  __attribute__((ext_vector_type(4)));
typedef unsigned int  u32x2  __attribute__((ext_vector_type(2)));

union FragU { u32x4 u; bf16x8 b; };

__device__ __forceinline__ unsigned pk2(float lo, float hi) {
    union { __hip_bfloat162 h2; unsigned u; } cv;
    cv.h2 = __float22bfloat162_rn(make_float2(lo, hi));
    return cv.u;
}
__device__ __forceinline__ float bf16lo_f(unsigned w) { return __uint_as_float(w << 16); }
__device__ __forceinline__ float bf16hi_f(unsigned w) { return __uint_as_float(w & 0xffff0000u); }

__device__ __forceinline__ const float* uni_ptr(const float* p) {
    unsigned long long u = (unsigned long long)p;
    unsigned lo = __builtin_amdgcn_readfirstlane((unsigned)u);
    unsigned hi = __builtin_amdgcn_readfirstlane((unsigned)(u >> 32));
    return (const float*)(((unsigned long long)hi << 32) | lo);
}

#define LBAR() do {                                                  \
    asm volatile("s_waitcnt lgkmcnt(0)" ::: "memory");               \
    __builtin_amdgcn_sched_barrier(0);                               \
    __builtin_amdgcn_s_barrier();                                    \
    __builtin_amdgcn_sched_barrier(0);                               \
} while (0)

// Kernel 1: per-block partial A over grid-strided 64-column tiles.
// ws layout: [block][entry = k*6 + m6]  (contiguous 6 KB per block, coalesced)
__global__ __launch_bounds__(NTHREADS, 4) void create_As_k1(
        const float* __restrict__ h, const float* __restrict__ rp,
        const float* __restrict__ W, float* __restrict__ ws, int nb)
{
    __shared__ unsigned short htile[BN * NCH];   // 32 KB bf16 [col][j], XOR-swizzled
    __shared__ unsigned short radlds[BN * NCH];  // 32 KB bf16 [col][k], XOR-swizzled
    __shared__ float uu6[6][BN];                 // 1.5 KB

    const int t    = threadIdx.x;
    const int wave = t >> 6;        // 0..7 -> k range [wave*32, wave*32+32)
    const int il   = t & 15;
    const int q    = (t >> 4) & 3;
    const int c    = t & 63;        // column within tile

    // ---- W fragments (MFMA A operand), register-resident ----
    FragU wf[2][8];
    #pragma unroll
    for (int kt = 0; kt < 2; ++kt) {
        const int k = wave * 32 + kt * 16 + il;
        const float* wr = W + (size_t)k * NCH + q * 8;
        #pragma unroll
        for (int jb = 0; jb < 8; ++jb) {
            f32x4 a = *(const f32x4*)(wr + jb * 32);
            f32x4 b = *(const f32x4*)(wr + jb * 32 + 4);
            FragU f;
            f.u[0] = pk2(a[0], a[1]);
            f.u[1] = pk2(a[2], a[3]);
            f.u[2] = pk2(b[0], b[1]);
            f.u[3] = pk2(b[2], b[3]);
            wf[kt][jb] = f;
        }
    }

    float acc6[8][6];
    #pragma unroll
    for (int s = 0; s < 8; ++s)
        #pragma unroll
        for (int m = 0; m < 6; ++m) acc6[s][m] = 0.0f;

    // SGPR-uniform h row bases: hb[pp] = h + (pp*8 + wave)*8 rows
    const float* hb0 = uni_ptr(h + (size_t)((0 * 8 + wave) * 8) * NNB);
    const float* hb1 = uni_ptr(h + (size_t)((1 * 8 + wave) * 8) * NNB);
    const float* hb2 = uni_ptr(h + (size_t)((2 * 8 + wave) * 8) * NNB);
    const float* hb3 = uni_ptr(h + (size_t)((3 * 8 + wave) * 8) * NNB);

    // rp prefetch (3 regs only)
    float px, py, pz;
    {
        const unsigned ii = (unsigned)(blockIdx.x * BN) + (unsigned)c;
        px = rp[ii];
        py = rp[(size_t)NNB + ii];
        pz = rp[2 * (size_t)NNB + ii];
    }

    for (int tile = blockIdx.x; tile < NTILES; tile += nb) {
        const unsigned idx = (unsigned)(tile * BN) + (unsigned)c;

        // ================= phase A =================
        float dd   = sqrtf(px * px + py * py + pz * pz);
        float invd = 1.0f / dd;
        if (t < 64) {
            float inv2 = invd * invd;
            uu6[0][c] = px * px * inv2;
            uu6[1][c] = px * py * inv2;
            uu6[2][c] = px * pz * inv2;
            uu6[3][c] = py * py * inv2;
            uu6[4][c] = py * pz * inv2;
            uu6[5][c] = pz * pz * inv2;
        }

        // radial chunk: k in [wave*32, wave*32+32) for column c, bf16, b128 writes
        {
            float s0, c0, s1, c1;
            __sincosf((float)(wave * 32 + 1) * dd, &s0, &c0);
            __sincosf(dd, &s1, &c1);
            unsigned rw[16];
            float s = s0, co = c0;
            #pragma unroll
            for (int m = 0; m < 16; ++m) {
                float v0 = s * invd;
                float ns = s * c1 + co * s1; co = co * c1 - s * s1; s = ns;
                float v1 = s * invd;
                ns = s * c1 + co * s1; co = co * c1 - s * s1; s = ns;
                rw[m] = pk2(v0, v1);
            }
            #pragma unroll
            for (int g = 0; g < 4; ++g) {
                u32x4 pk = { rw[g * 4], rw[g * 4 + 1], rw[g * 4 + 2], rw[g * 4 + 3] };
                unsigned off = ((unsigned)(c * 512 + wave * 64 + g * 16)) ^ ((unsigned)(c & 7) << 4);
                *(u32x4*)((char*)radlds + off) = pk;
            }
        }

        // rp prefetch for next tile (3 regs, latency hidden under phase B)
        {
            const int nxt = tile + nb;
            if (nxt < NTILES) {
                const unsigned ii = (unsigned)(nxt * BN) + (unsigned)c;
                px = rp[ii];
                py = rp[(size_t)NNB + ii];
                pz = rp[2 * (size_t)NNB + ii];
            }
        }

        // h staging: 4 chunks of 8 rows (peak 8 live load regs, no spill)
        #pragma unroll
        for (int pp = 0; pp < 4; ++pp) {
            const float* hbp = (pp == 0) ? hb0 : (pp == 1) ? hb1 : (pp == 2) ? hb2 : hb3;
            float v[8];
            #pragma unroll
            for (int j = 0; j < 8; ++j) v[j] = hbp[(size_t)j * NNB + idx];
            u32x4 pk;
            pk[0] = pk2(v[0], v[1]);
            pk[1] = pk2(v[2], v[3]);
            pk[2] = pk2(v[4], v[5]);
            pk[3] = pk2(v[6], v[7]);
            const int jp = pp * 8 + wave;
            unsigned off = ((unsigned)(c * 512 + jp * 16)) ^ ((unsigned)(c & 7) << 4);
            *(u32x4*)((char*)htile + off) = pk;
        }

        LBAR();

        // ================= phase B: MFMA + fused epilogue =================
        #pragma unroll
        for (int cb = 0; cb < 4; ++cb) {
            const int ic = cb * 16 + il;
            f32x4 acc0 = {0.f, 0.f, 0.f, 0.f};
            f32x4 acc1 = {0.f, 0.f, 0.f, 0.f};
            const unsigned rbase = (unsigned)(ic * 512);
            const unsigned sw    = ((unsigned)(ic & 7)) << 4;
            #pragma unroll
            for (int jb = 0; jb < 8; ++jb) {
                unsigned off = (rbase + (unsigned)(jb * 64 + q * 16)) ^ sw;
                FragU bfr;
                bfr.u = *(const u32x4*)((const char*)htile + off);
                acc0 = __builtin_amdgcn_mfma_f32_16x16x32_bf16(wf[0][jb].b, bfr.b, acc0, 0, 0, 0);
                acc1 = __builtin_amdgcn_mfma_f32_16x16x32_bf16(wf[1][jb].b, bfr.b, acc1, 0, 0, 0);
            }
            const int kb = wave * 32 + q * 4;
            u32x2 r0 = *(const u32x2*)((const char*)radlds + ((rbase + (unsigned)(kb * 2)) ^ sw));
            u32x2 r1 = *(const u32x2*)((const char*)radlds + ((rbase + (unsigned)((kb + 16) * 2)) ^ sw));
            float rad0[4] = { bf16lo_f(r0[0]), bf16hi_f(r0[0]), bf16lo_f(r0[1]), bf16hi_f(r0[1]) };
            float rad1[4] = { bf16lo_f(r1[0]), bf16hi_f(r1[0]), bf16lo_f(r1[1]), bf16hi_f(r1[1]) };
            const float u0 = uu6[0][ic], u1 = uu6[1][ic], u2 = uu6[2][ic];
            const float u3 = uu6[3][ic], u4 = uu6[4][ic], u5 = uu6[5][ic];
            #pragma unroll
            for (int r = 0; r < 4; ++r) {
                float m0 = rad0[r] * acc0[r];
                acc6[r][0] += m0 * u0; acc6[r][1] += m0 * u1; acc6[r][2] += m0 * u2;
                acc6[r][3] += m0 * u3; acc6[r][4] += m0 * u4; acc6[r][5] += m0 * u5;
                float m1 = rad1[r] * acc1[r];
                acc6[4 + r][0] += m1 * u0; acc6[4 + r][1] += m1 * u1; acc6[4 + r][2] += m1 * u2;
                acc6[4 + r][3] += m1 * u3; acc6[4 + r][4] += m1 * u4; acc6[4 + r][5] += m1 * u5;
            }
        }

        __builtin_amdgcn_sched_barrier(0);
        __builtin_amdgcn_s_barrier();        // LDS reads done; next phase A may overwrite
        __builtin_amdgcn_sched_barrier(0);
    }

    // ---- reduce over the 16 column-lanes, store contiguous per-block partial ----
    #pragma unroll
    for (int s = 0; s < 8; ++s)
        #pragma unroll
        for (int m = 0; m < 6; ++m) {
            float v = acc6[s][m];
            v += __shfl_xor(v, 1);
            v += __shfl_xor(v, 2);
            v += __shfl_xor(v, 4);
            v += __shfl_xor(v, 8);
            acc6[s][m] = v;
        }
    if (il == 0) {
        float* dst = ws + (size_t)blockIdx.x * NENT;
        #pragma unroll
        for (int kt = 0; kt < 2; ++kt)
            #pragma unroll
            for (int r = 0; r < 4; ++r) {
                const int k = wave * 32 + kt * 16 + q * 4 + r;
                #pragma unroll
                for (int m = 0; m < 6; ++m)
                    dst[k * 6 + m] = acc6[kt * 4 + r][m];
            }
    }
}

// Kernel 2: 24 blocks x 512 threads. Block eb owns entries [eb*64, eb*64+64).
// Wave w sums blocks b = w, w+8, ... (coalesced 256B rows); LDS reduce; direct store.
__global__ void create_As_k2(const float* __restrict__ ws, float* __restrict__ out,
                             int nb)
{
    __shared__ float red[8][64];
    const int eb = blockIdx.x;                  // 0..23  (1536/64)
    const int w  = threadIdx.x >> 6;
    const int l  = threadIdx.x & 63;
    float s = 0.f;
    #pragma unroll 4
    for (int b = w; b < nb; b += 8)
        s += ws[(size_t)b * NENT + (unsigned)(eb * 64 + l)];
    red[w][l] = s;
    __syncthreads();
    if (w == 0) {
        float v = red[0][l] + red[1][l] + red[2][l] + red[3][l]
                + red[4][l] + red[5][l] + red[6][l] + red[7][l];
        const int e  = eb * 64 + l;
        const int k  = e / 6;
        const int m6 = e - k * 6;
        const int d  = (m6 < 3) ? 0 : ((m6 < 5) ? 1 : 2);
        const int e2 = (m6 < 3) ? m6 : ((m6 < 5) ? (m6 - 2) : 2);
        out[k * 9 + d * 3 + e2] = v;
        if (d != e2) out[k * 9 + e2 * 3 + d] = v;
    }
}

extern "C" void kernel_launch(void* const* d_in, const int* in_sizes, int n_in,
                              void* d_out, int out_size, void* d_ws, size_t ws_size,
                              hipStream_t stream)
{
    const float* h  = (const float*)d_in[0];
    const float* rp = (const float*)d_in[1];
    const float* W  = (const float*)d_in[2];
    float* out = (float*)d_out;
    float* ws  = (float*)d_ws;

    const size_t per_block = (size_t)NENT * sizeof(float);   // 6 KB
    int nb = (int)(ws_size / per_block);
    if (nb > 1024)   nb = 1024;
    if (nb > NTILES) nb = NTILES;
    if (nb < 1)      nb = 1;

    hipLaunchKernelGGL(create_As_k1, dim3(nb), dim3(NTHREADS), 0, stream,
                       h, rp, W, ws, nb);
    hipLaunchKernelGGL(create_As_k2, dim3(NENT / 64), dim3(512), 0, stream,
                       ws, out, nb);
}

// Round 4
// 129.456 us; speedup vs baseline: 3.2004x; 3.2004x over previous
//
#include <hip/hip_runtime.h>
#include <hip/hip_bf16.h>

#define NCH      256
#define NNB      262144
#define BN       64
#define NTILES   (NNB / BN)
#define NTHREADS 512
#define NENT     (NCH * 6)

typedef __bf16        bf16x8 __attribute__((ext_vector_type(8)));
typedef float         f32x4  __attribute__((ext_vector_type(4)));
typedef unsigned int  u32x4  __attribute__((ext_vector_type(4)));
typedef unsigned int  u32x2  __attribute__((ext_vector_type(2)));
typedef short         v4s    __attribute__((ext_vector_type(4)));

union FragU  { u32x4 u; bf16x8 b; };
union Frag2U { u32x2 u; v4s    s; };

__device__ __forceinline__ unsigned pk2(float lo, float hi) {
    union { __hip_bfloat162 h2; unsigned u; } cv;
    cv.h2 = __float22bfloat162_rn(make_float2(lo, hi));
    return cv.u;
}
__device__ __forceinline__ float bf16lo_f(unsigned w) { return __uint_as_float(w << 16); }
__device__ __forceinline__ float bf16hi_f(unsigned w) { return __uint_as_float(w & 0xffff0000u); }

__device__ __forceinline__ const float* uni_ptr(const float* p) {
    unsigned long long u = (unsigned long long)p;
    unsigned lo = __builtin_amdgcn_readfirstlane((unsigned)u);
    unsigned hi = __builtin_amdgcn_readfirstlane((unsigned)(u >> 32));
    return (const float*)(((unsigned long long)hi << 32) | lo);
}

#define LBAR() do {                                                  \
    asm volatile("s_waitcnt lgkmcnt(0)" ::: "memory");               \
    __builtin_amdgcn_sched_barrier(0);                               \
    __builtin_amdgcn_s_barrier();                                    \
    __builtin_amdgcn_sched_barrier(0);                               \
} while (0)

// K1: per-block partial A over grid-strided 64-col tiles.
// GEMM1 (swapped): hp^T[col][k] = h_tile^T · W^T  via mfma(h_frag, w_frag)
// GEMM2: A[k][de] += (radial*hp)[k][col] · G[col][de]  via mfma_16x16x16bf16_1k
// ws layout: [block][entry = k*6 + m6]
__global__ __launch_bounds__(NTHREADS, 2) void create_As_k1(
        const float* __restrict__ h, const float* __restrict__ rp,
        const float* __restrict__ W, float* __restrict__ ws, int nb)
{
    __shared__ unsigned short htile[BN * NCH];   // [col][j]  32 KB, byte ^ ((col&7)<<4)
    __shared__ unsigned short radT[NCH * BN];    // [k][col]  32 KB, byte ^ ((k&7)<<3)
    __shared__ unsigned short gT[16 * BN];       // [de][col]  2 KB, byte ^ ((de&7)<<3)

    const int t    = threadIdx.x;
    const int wave = t >> 6;        // k range [wave*32, wave*32+32)
    const int il   = t & 15;
    const int q    = (t >> 4) & 3;
    const int c    = t & 63;
    const int k0   = wave * 32;

    // zero G rows once (rows 6..15 must be finite; rows 0..5 rewritten per tile)
    if (t < 512) ((unsigned*)gT)[t] = 0u;

    // ---- W fragments: lane holds W[k0+kt*16+il][jb*32 + q*8 + e] ----
    FragU wf[2][8];
    #pragma unroll
    for (int kt = 0; kt < 2; ++kt) {
        const float* wr = W + (size_t)(k0 + kt * 16 + il) * NCH + q * 8;
        #pragma unroll
        for (int jb = 0; jb < 8; ++jb) {
            f32x4 a = *(const f32x4*)(wr + jb * 32);
            f32x4 b = *(const f32x4*)(wr + jb * 32 + 4);
            FragU f;
            f.u[0] = pk2(a[0], a[1]);
            f.u[1] = pk2(a[2], a[3]);
            f.u[2] = pk2(b[0], b[1]);
            f.u[3] = pk2(b[2], b[3]);
            wf[kt][jb] = f;
        }
    }

    f32x4 acc2[2];
    acc2[0] = (f32x4){0.f, 0.f, 0.f, 0.f};
    acc2[1] = (f32x4){0.f, 0.f, 0.f, 0.f};

    // SGPR-uniform h chunk bases
    const float* hb0 = uni_ptr(h + (size_t)((0 * 8 + wave) * 8) * NNB);
    const float* hb1 = uni_ptr(h + (size_t)((1 * 8 + wave) * 8) * NNB);
    const float* hb2 = uni_ptr(h + (size_t)((2 * 8 + wave) * 8) * NNB);
    const float* hb3 = uni_ptr(h + (size_t)((3 * 8 + wave) * 8) * NNB);

    // ---- prefetch state: rp (3 regs) + h packed bf16 (16 regs) ----
    float px, py, pz;
    unsigned hvp[16];
    {
        const unsigned ii = (unsigned)(blockIdx.x * BN) + (unsigned)c;
        px = rp[ii];
        py = rp[(size_t)NNB + ii];
        pz = rp[2 * (size_t)NNB + ii];
        #pragma unroll
        for (int pp = 0; pp < 4; ++pp) {
            const float* hbp = (pp == 0) ? hb0 : (pp == 1) ? hb1 : (pp == 2) ? hb2 : hb3;
            float v[8];
            #pragma unroll
            for (int j = 0; j < 8; ++j) v[j] = hbp[(size_t)j * NNB + ii];
            hvp[pp * 4 + 0] = pk2(v[0], v[1]);
            hvp[pp * 4 + 1] = pk2(v[2], v[3]);
            hvp[pp * 4 + 2] = pk2(v[4], v[5]);
            hvp[pp * 4 + 3] = pk2(v[6], v[7]);
        }
    }
    __syncthreads();   // gT zero-init visible before first phase-A G writes

    for (int tile = blockIdx.x; tile < NTILES; tile += nb) {
        // ================= phase A: regs -> LDS =================
        float dd   = sqrtf(px * px + py * py + pz * pz);
        float invd = 1.0f / dd;

        if (t < 64) {   // G table rows 0..5: ux*ux, ux*uy, ux*uz, uy*uy, uy*uz, uz*uz
            float inv2 = invd * invd;
            float g[6] = { px * px * inv2, px * py * inv2, px * pz * inv2,
                           py * py * inv2, py * pz * inv2, pz * pz * inv2 };
            #pragma unroll
            for (int de = 0; de < 6; ++de) {
                unsigned off = ((unsigned)(de * 128 + c * 2)) ^ ((unsigned)de << 3);
                *(unsigned short*)((char*)gT + off) = (unsigned short)(pk2(g[de], 0.f) & 0xffffu);
            }
        }

        // radial: k in [k0, k0+32) for column c -> radT[k][c] bf16 (scatter u16)
        {
            float s0, c0, s1, c1;
            __sincosf((float)(k0 + 1) * dd, &s0, &c0);
            __sincosf(dd, &s1, &c1);
            float s = s0, co = c0;
            #pragma unroll
            for (int m = 0; m < 32; ++m) {
                const int k = k0 + m;
                unsigned off = ((unsigned)(k * 128 + c * 2)) ^ (((unsigned)(k & 7)) << 3);
                *(unsigned short*)((char*)radT + off) =
                    (unsigned short)(pk2(s * invd, 0.f) & 0xffffu);
                float ns = s * c1 + co * s1; co = co * c1 - s * s1; s = ns;
            }
        }

        // h tile from prefetched packed regs: [col][j], b128 writes
        #pragma unroll
        for (int pp = 0; pp < 4; ++pp) {
            u32x4 pk = { hvp[pp * 4 + 0], hvp[pp * 4 + 1], hvp[pp * 4 + 2], hvp[pp * 4 + 3] };
            unsigned off = ((unsigned)(c * 512 + (pp * 8 + wave) * 16)) ^ (((unsigned)(c & 7)) << 4);
            *(u32x4*)((char*)htile + off) = pk;
        }

        LBAR();

        // ================= phase B =================
        // prefetch next tile (loads stay in flight across next LBAR's s_barrier)
        {
            const int nxt = tile + nb;
            const int lt  = (nxt < NTILES) ? nxt : tile;
            const unsigned ii = (unsigned)(lt * BN) + (unsigned)c;
            px = rp[ii];
            py = rp[(size_t)NNB + ii];
            pz = rp[2 * (size_t)NNB + ii];
            #pragma unroll
            for (int pp = 0; pp < 4; ++pp) {
                const float* hbp = (pp == 0) ? hb0 : (pp == 1) ? hb1 : (pp == 2) ? hb2 : hb3;
                float v[8];
                #pragma unroll
                for (int j = 0; j < 8; ++j) v[j] = hbp[(size_t)j * NNB + ii];
                hvp[pp * 4 + 0] = pk2(v[0], v[1]);
                hvp[pp * 4 + 1] = pk2(v[2], v[3]);
                hvp[pp * 4 + 2] = pk2(v[4], v[5]);
                hvp[pp * 4 + 3] = pk2(v[6], v[7]);
            }
        }
        __builtin_amdgcn_sched_barrier(0);

        const unsigned swh = (((unsigned)(il & 7)) << 4);
        const unsigned swr = (((unsigned)(il & 7)) << 3);
        #pragma unroll
        for (int cb = 0; cb < 4; ++cb) {
            const int colb = cb * 16;
            // G b-frag: G[colb + q*4 + e][de = il]
            Frag2U gf;
            gf.u = *(const u32x2*)((const char*)gT +
                    ((((unsigned)(il * 128 + (colb + q * 4) * 2))) ^ (((unsigned)(il & 7)) << 3)));

            // GEMM1 (swapped): hp^T: lane -> col = colb + q*4 + r, k = k0 + kt*16 + il
            f32x4 hp0 = {0.f, 0.f, 0.f, 0.f};
            f32x4 hp1 = {0.f, 0.f, 0.f, 0.f};
            const unsigned hbase = (unsigned)((colb + il) * 512);
            #pragma unroll
            for (int jb = 0; jb < 8; ++jb) {
                unsigned off = (hbase + (unsigned)(jb * 64 + q * 16)) ^ swh;
                FragU bfr;
                bfr.u = *(const u32x4*)((const char*)htile + off);
                hp0 = __builtin_amdgcn_mfma_f32_16x16x32_bf16(bfr.b, wf[0][jb].b, hp0, 0, 0, 0);
                hp1 = __builtin_amdgcn_mfma_f32_16x16x32_bf16(bfr.b, wf[1][jb].b, hp1, 0, 0, 0);
            }

            // radial b64: radT[k0(+16)+il][colb + q*4 .. +3]
            u32x2 r0 = *(const u32x2*)((const char*)radT +
                    ((unsigned)((k0 + il) * 128 + (colb + q * 4) * 2) ^ swr));
            u32x2 r1 = *(const u32x2*)((const char*)radT +
                    ((unsigned)((k0 + 16 + il) * 128 + (colb + q * 4) * 2) ^ swr));

            // m = radial * hp, pack to bf16 a-frag; GEMM2 accumulate
            Frag2U a0, a1;
            a0.u[0] = pk2(bf16lo_f(r0[0]) * hp0[0], bf16hi_f(r0[0]) * hp0[1]);
            a0.u[1] = pk2(bf16lo_f(r0[1]) * hp0[2], bf16hi_f(r0[1]) * hp0[3]);
            a1.u[0] = pk2(bf16lo_f(r1[0]) * hp1[0], bf16hi_f(r1[0]) * hp1[1]);
            a1.u[1] = pk2(bf16lo_f(r1[1]) * hp1[2], bf16hi_f(r1[1]) * hp1[3]);
            acc2[0] = __builtin_amdgcn_mfma_f32_16x16x16bf16_1k(a0.s, gf.s, acc2[0], 0, 0, 0);
            acc2[1] = __builtin_amdgcn_mfma_f32_16x16x16bf16_1k(a1.s, gf.s, acc2[1], 0, 0, 0);
        }

        __builtin_amdgcn_sched_barrier(0);
        __builtin_amdgcn_s_barrier();        // LDS reads done; next phase A may overwrite
        __builtin_amdgcn_sched_barrier(0);
    }

    // ---- store: lane holds A[k = k0 + kt*16 + q*4 + r][de = il] ----
    if (il < 6) {
        float* dst = ws + (size_t)blockIdx.x * NENT;
        #pragma unroll
        for (int kt = 0; kt < 2; ++kt)
            #pragma unroll
            for (int r = 0; r < 4; ++r) {
                const int k = k0 + kt * 16 + q * 4 + r;
                dst[k * 6 + il] = acc2[kt][r];
            }
    }
}

// K2: 24 blocks x 512. Block eb owns entries [eb*64, +64); coalesced rows; LDS reduce.
__global__ void create_As_k2(const float* __restrict__ ws, float* __restrict__ out,
                             int nb)
{
    __shared__ float red[8][64];
    const int eb = blockIdx.x;
    const int w  = threadIdx.x >> 6;
    const int l  = threadIdx.x & 63;
    float s = 0.f;
    #pragma unroll 4
    for (int b = w; b < nb; b += 8)
        s += ws[(size_t)b * NENT + (unsigned)(eb * 64 + l)];
    red[w][l] = s;
    __syncthreads();
    if (w == 0) {
        float v = red[0][l] + red[1][l] + red[2][l] + red[3][l]
                + red[4][l] + red[5][l] + red[6][l] + red[7][l];
        const int e  = eb * 64 + l;
        const int k  = e / 6;
        const int m6 = e - k * 6;
        const int d  = (m6 < 3) ? 0 : ((m6 < 5) ? 1 : 2);
        const int e2 = (m6 < 3) ? m6 : ((m6 < 5) ? (m6 - 2) : 2);
        out[k * 9 + d * 3 + e2] = v;
        if (d != e2) out[k * 9 + e2 * 3 + d] = v;
    }
}

extern "C" void kernel_launch(void* const* d_in, const int* in_sizes, int n_in,
                              void* d_out, int out_size, void* d_ws, size_t ws_size,
                              hipStream_t stream)
{
    const float* h  = (const float*)d_in[0];
    const float* rp = (const float*)d_in[1];
    const float* W  = (const float*)d_in[2];
    float* out = (float*)d_out;
    float* ws  = (float*)d_ws;

    const size_t per_block = (size_t)NENT * sizeof(float);   // 6 KB
    int nb = (int)(ws_size / per_block);
    if (nb > 1024)   nb = 1024;
    if (nb > NTILES) nb = NTILES;
    if (nb < 1)      nb = 1;

    hipLaunchKernelGGL(create_As_k1, dim3(nb), dim3(NTHREADS), 0, stream,
                       h, rp, W, ws, nb);
    hipLaunchKernelGGL(create_As_k2, dim3(NENT / 64), dim3(512), 0, stream,
                       ws, out, nb);
}

// Round 5
// 76.875 us; speedup vs baseline: 5.3894x; 1.6840x over previous
//
#include <hip/hip_runtime.h>
#include <hip/hip_bf16.h>

#define NCH      256
#define NNB      262144
#define BN       64
#define NTILES   (NNB / BN)   // 4096
#define NB       256          // K1 grid: 1 block per CU
#define ITPB     (NTILES / NB) // 16 tiles per block
#define NENT     (NCH * 6)

typedef __bf16        bf16x8 __attribute__((ext_vector_type(8)));
typedef float         f32x4  __attribute__((ext_vector_type(4)));
typedef unsigned int  u32x4  __attribute__((ext_vector_type(4)));
typedef unsigned int  u32x2  __attribute__((ext_vector_type(2)));
typedef short         v4s    __attribute__((ext_vector_type(4)));

union FragU  { u32x4 u; bf16x8 b; };
union Frag2U { u32x2 u; v4s    s; };

__device__ __forceinline__ unsigned pk2(float lo, float hi) {
    union { __hip_bfloat162 h2; unsigned u; } cv;
    cv.h2 = __float22bfloat162_rn(make_float2(lo, hi));
    return cv.u;
}

__device__ __forceinline__ const float* uni_ptr(const float* p) {
    unsigned long long u = (unsigned long long)p;
    unsigned lo = __builtin_amdgcn_readfirstlane((unsigned)u);
    unsigned hi = __builtin_amdgcn_readfirstlane((unsigned)(u >> 32));
    return (const float*)(((unsigned long long)hi << 32) | lo);
}

// raw barrier: LDS writes visible, but global loads stay in flight (no vmcnt drain)
#define LBAR() do {                                                  \
    asm volatile("s_waitcnt lgkmcnt(0)" ::: "memory");               \
    __builtin_amdgcn_sched_barrier(0);                               \
    __builtin_amdgcn_s_barrier();                                    \
    __builtin_amdgcn_sched_barrier(0);                               \
} while (0)

// One iteration: compute tile from buf P; prepare tile+NB into buf P^1.
// CUR holds rp(tile+NB) [arrived]; NXT receives rp(tile+2NB) [issued here].
// hv holds h(tile+NB) fp32 [arrived]; re-issued for tile+2NB after packing.
#define ITER(P, CUR, NXT, TILE_EXPR)                                               \
{                                                                                  \
    const int tile = (TILE_EXPR);                                                  \
    const int tn1  = tile + NB;                                                    \
    const int tn2  = tile + 2 * NB;                                                \
    {   /* issue rp(tn2) -> NXT (consumed next iteration's A) */                   \
        const int lt = (tn2 < NTILES) ? tn2 : tile;                                \
        const unsigned ii = (unsigned)(lt * BN) + (unsigned)c;                     \
        NXT[0] = rp[ii];                                                           \
        NXT[1] = rp[(size_t)NNB + ii];                                             \
        NXT[2] = rp[2 * (size_t)NNB + ii];                                         \
    }                                                                              \
    __builtin_amdgcn_sched_barrier(0);                                             \
    /* ---- B: compute tile from htile[P], dtab[P], gT[P] ---- */                  \
    _Pragma("unroll")                                                              \
    for (int cb = 0; cb < 4; ++cb) {                                               \
        const int colb = cb * 16;                                                  \
        Frag2U gf;                                                                 \
        gf.u = *(const u32x2*)((const char*)gT[P] +                                \
               (((unsigned)(il * 128 + (colb + q * 4) * 2)) ^                      \
                (((unsigned)(il & 7)) << 3)));                                     \
        f32x4 hpA = {0.f, 0.f, 0.f, 0.f}, hpB = {0.f, 0.f, 0.f, 0.f};              \
        const unsigned rb = (unsigned)((colb + il) * 512);                         \
        const unsigned sw = ((unsigned)(il & 7)) << 4;                             \
        _Pragma("unroll")                                                          \
        for (int jb = 0; jb < 8; jb += 2) {                                        \
            FragU f0, f1;                                                          \
            f0.u = *(const u32x4*)((const char*)htile[P] +                         \
                   ((rb + (unsigned)(jb * 64 + q * 16)) ^ sw));                    \
            f1.u = *(const u32x4*)((const char*)htile[P] +                         \
                   ((rb + (unsigned)((jb + 1) * 64 + q * 16)) ^ sw));              \
            hpA = __builtin_amdgcn_mfma_f32_16x16x32_bf16(f0.b, wf[jb].b, hpA, 0, 0, 0);     \
            hpB = __builtin_amdgcn_mfma_f32_16x16x32_bf16(f1.b, wf[jb + 1].b, hpB, 0, 0, 0); \
        }                                                                          \
        f32x4 d4 = *(const f32x4*)&dtab[P][0][colb + q * 4];                       \
        f32x4 i4 = *(const f32x4*)&dtab[P][1][colb + q * 4];                       \
        float m0 = __sinf(fk * d4[0]) * i4[0] * (hpA[0] + hpB[0]);                 \
        float m1 = __sinf(fk * d4[1]) * i4[1] * (hpA[1] + hpB[1]);                 \
        float m2 = __sinf(fk * d4[2]) * i4[2] * (hpA[2] + hpB[2]);                 \
        float m3 = __sinf(fk * d4[3]) * i4[3] * (hpA[3] + hpB[3]);                 \
        Frag2U af;                                                                 \
        af.u[0] = pk2(m0, m1);                                                     \
        af.u[1] = pk2(m2, m3);                                                     \
        acc = __builtin_amdgcn_mfma_f32_16x16x16bf16_1k(af.s, gf.s, acc, 0, 0, 0); \
    }                                                                              \
    __builtin_amdgcn_sched_barrier(0);                                             \
    /* ---- A: prep tile tn1 into buf P^1 (vmcnt waits land here) ---- */          \
    if (tn1 < NTILES) {                                                            \
        u32x4 w0, w1;                                                              \
        w0[0] = pk2(hv[0], hv[1]);   w0[1] = pk2(hv[2], hv[3]);                    \
        w0[2] = pk2(hv[4], hv[5]);   w0[3] = pk2(hv[6], hv[7]);                    \
        w1[0] = pk2(hv[8], hv[9]);   w1[1] = pk2(hv[10], hv[11]);                  \
        w1[2] = pk2(hv[12], hv[13]); w1[3] = pk2(hv[14], hv[15]);                  \
        const unsigned swc = ((unsigned)(c & 7)) << 4;                             \
        *(u32x4*)((char*)htile[(P) ^ 1] +                                          \
                  (((unsigned)(c * 512 + wave * 32)) ^ swc)) = w0;                 \
        *(u32x4*)((char*)htile[(P) ^ 1] +                                          \
                  (((unsigned)(c * 512 + wave * 32 + 16)) ^ swc)) = w1;            \
        float dd = sqrtf(CUR[0] * CUR[0] + CUR[1] * CUR[1] + CUR[2] * CUR[2]);     \
        float iv = 1.0f / dd;                                                      \
        if (t < 64) {                                                              \
            dtab[(P) ^ 1][0][c] = dd;                                              \
            dtab[(P) ^ 1][1][c] = iv;                                              \
            float i2 = iv * iv;                                                    \
            float gg[6] = { CUR[0] * CUR[0] * i2, CUR[0] * CUR[1] * i2,            \
                            CUR[0] * CUR[2] * i2, CUR[1] * CUR[1] * i2,            \
                            CUR[1] * CUR[2] * i2, CUR[2] * CUR[2] * i2 };          \
            _Pragma("unroll")                                                      \
            for (int de = 0; de < 6; ++de) {                                       \
                unsigned off = ((unsigned)(de * 128 + c * 2)) ^                    \
                               (((unsigned)de) << 3);                              \
                *(unsigned short*)((char*)gT[(P) ^ 1] + off) =                     \
                    (unsigned short)(pk2(gg[de], 0.f) & 0xffffu);                  \
            }                                                                      \
        }                                                                          \
        const int lt2 = (tn2 < NTILES) ? tn2 : tile;                               \
        const unsigned ii2 = (unsigned)(lt2 * BN) + (unsigned)c;                   \
        _Pragma("unroll")                                                          \
        for (int j = 0; j < 16; ++j) hv[j] = hwb[(size_t)j * NNB + ii2];           \
    }                                                                              \
    LBAR();                                                                        \
}

// K1: 1024 threads = 16 waves; wave owns k in [wave*16, wave*16+16).
// GEMM1 (swapped): hp[col][k] via mfma(h_frag, w_frag); GEMM2: A[k][de] via 16x16x16.
// ws layout: [block][entry = k*6 + m6]
__global__ __launch_bounds__(1024, 1) void create_As_k1(
        const float* __restrict__ h, const float* __restrict__ rp,
        const float* __restrict__ W, float* __restrict__ ws)
{
    __shared__ unsigned short htile[2][BN * NCH];        // 2 x 32 KB [col][j], ^((c&7)<<4)
    __shared__ unsigned short gT[2][16 * BN];            // 2 x 2 KB [de][col], ^((de&7)<<3)
    __shared__ __align__(16) float dtab[2][2][BN];       // [p][{d,invd}][col]

    const int t    = threadIdx.x;
    const int wave = t >> 6;        // 0..15
    const int il   = t & 15;
    const int q    = (t >> 4) & 3;
    const int c    = t & 63;
    const int k0   = wave * 16;
    const float fk = (float)(k0 + il + 1);

    ((unsigned*)gT)[t] = 0u;        // 1024 u32 == sizeof(gT)/4: rows 6..15 stay zero

    // W fragments: lane holds W[k0+il][jb*32 + q*8 + e], e=0..7  (32 VGPR)
    FragU wf[8];
    {
        const float* wr = W + (size_t)(k0 + il) * NCH + q * 8;
        #pragma unroll
        for (int jb = 0; jb < 8; ++jb) {
            f32x4 a = *(const f32x4*)(wr + jb * 32);
            f32x4 b = *(const f32x4*)(wr + jb * 32 + 4);
            wf[jb].u[0] = pk2(a[0], a[1]);
            wf[jb].u[1] = pk2(a[2], a[3]);
            wf[jb].u[2] = pk2(b[0], b[1]);
            wf[jb].u[3] = pk2(b[2], b[3]);
        }
    }

    f32x4 acc = {0.f, 0.f, 0.f, 0.f};

    const float* hwb = uni_ptr(h + (size_t)(wave * 16) * NNB);

    float hv[16];
    float pA[3], pB[3];

    const int tile0 = blockIdx.x;

    __syncthreads();   // gT zero-init + wf reads done before prologue LDS writes

    // -------- prologue: stage tile0 into buf 0; issue tile1 loads --------
    {
        const unsigned ii = (unsigned)(tile0 * BN) + (unsigned)c;
        pB[0] = rp[ii]; pB[1] = rp[(size_t)NNB + ii]; pB[2] = rp[2 * (size_t)NNB + ii];
        #pragma unroll
        for (int j = 0; j < 16; ++j) hv[j] = hwb[(size_t)j * NNB + ii];

        u32x4 w0, w1;
        w0[0] = pk2(hv[0], hv[1]);   w0[1] = pk2(hv[2], hv[3]);
        w0[2] = pk2(hv[4], hv[5]);   w0[3] = pk2(hv[6], hv[7]);
        w1[0] = pk2(hv[8], hv[9]);   w1[1] = pk2(hv[10], hv[11]);
        w1[2] = pk2(hv[12], hv[13]); w1[3] = pk2(hv[14], hv[15]);
        const unsigned swc = ((unsigned)(c & 7)) << 4;
        *(u32x4*)((char*)htile[0] + (((unsigned)(c * 512 + wave * 32)) ^ swc)) = w0;
        *(u32x4*)((char*)htile[0] + (((unsigned)(c * 512 + wave * 32 + 16)) ^ swc)) = w1;

        float dd = sqrtf(pB[0] * pB[0] + pB[1] * pB[1] + pB[2] * pB[2]);
        float iv = 1.0f / dd;
        if (t < 64) {
            dtab[0][0][c] = dd; dtab[0][1][c] = iv;
            float i2 = iv * iv;
            float gg[6] = { pB[0] * pB[0] * i2, pB[0] * pB[1] * i2, pB[0] * pB[2] * i2,
                            pB[1] * pB[1] * i2, pB[1] * pB[2] * i2, pB[2] * pB[2] * i2 };
            #pragma unroll
            for (int de = 0; de < 6; ++de) {
                unsigned off = ((unsigned)(de * 128 + c * 2)) ^ (((unsigned)de) << 3);
                *(unsigned short*)((char*)gT[0] + off) =
                    (unsigned short)(pk2(gg[de], 0.f) & 0xffffu);
            }
        }
        // issue tile1: rp -> pA, h -> hv (consumed in iteration 0's A-phase)
        const unsigned i1 = (unsigned)((tile0 + NB) * BN) + (unsigned)c;
        pA[0] = rp[i1]; pA[1] = rp[(size_t)NNB + i1]; pA[2] = rp[2 * (size_t)NNB + i1];
        #pragma unroll
        for (int j = 0; j < 16; ++j) hv[j] = hwb[(size_t)j * NNB + i1];
    }
    LBAR();

    #pragma unroll 1
    for (int it2 = 0; it2 < ITPB; it2 += 2) {
        const int tb = tile0 + it2 * NB;
        ITER(0, pA, pB, tb)
        ITER(1, pB, pA, tb + NB)
    }

    // ---- store: lane holds A[k = k0 + q*4 + r][de = il] ----
    if (il < 6) {
        float* dst = ws + (size_t)blockIdx.x * NENT;
        #pragma unroll
        for (int r = 0; r < 4; ++r)
            dst[(k0 + q * 4 + r) * 6 + il] = acc[r];
    }
}

// K2: 24 blocks x 512. Block eb owns entries [eb*64, +64); coalesced rows; LDS reduce.
__global__ void create_As_k2(const float* __restrict__ ws, float* __restrict__ out)
{
    __shared__ float red[8][64];
    const int eb = blockIdx.x;
    const int w  = threadIdx.x >> 6;
    const int l  = threadIdx.x & 63;
    float s = 0.f;
    #pragma unroll 4
    for (int b = w; b < NB; b += 8)
        s += ws[(size_t)b * NENT + (unsigned)(eb * 64 + l)];
    red[w][l] = s;
    __syncthreads();
    if (w == 0) {
        float v = red[0][l] + red[1][l] + red[2][l] + red[3][l]
                + red[4][l] + red[5][l] + red[6][l] + red[7][l];
        const int e  = eb * 64 + l;
        const int k  = e / 6;
        const int m6 = e - k * 6;
        const int d  = (m6 < 3) ? 0 : ((m6 < 5) ? 1 : 2);
        const int e2 = (m6 < 3) ? m6 : ((m6 < 5) ? (m6 - 2) : 2);
        out[k * 9 + d * 3 + e2] = v;
        if (d != e2) out[k * 9 + e2 * 3 + d] = v;
    }
}

extern "C" void kernel_launch(void* const* d_in, const int* in_sizes, int n_in,
                              void* d_out, int out_size, void* d_ws, size_t ws_size,
                              hipStream_t stream)
{
    const float* h  = (const float*)d_in[0];
    const float* rp = (const float*)d_in[1];
    const float* W  = (const float*)d_in[2];
    float* out = (float*)d_out;
    float* ws  = (float*)d_ws;

    hipLaunchKernelGGL(create_As_k1, dim3(NB), dim3(1024), 0, stream, h, rp, W, ws);
    hipLaunchKernelGGL(create_As_k2, dim3(NENT / 64), dim3(512), 0, stream, ws, out);
}